// Round 3
// baseline (675.349 us; speedup 1.0000x reference)
//
#include <hip/hip_runtime.h>
#include <hip/hip_bf16.h>

typedef __hip_bfloat16 bf16;
typedef unsigned short u16;

#define HC 256     // H*C
#define CDIM 64
#define MAXD 512   // per-wave LDS softmax buffer capacity (edges per node)

__device__ __forceinline__ float b2f(u16 u){
  union { unsigned int i; float f; } c; c.i = ((unsigned)u) << 16; return c.f;
}
__device__ __forceinline__ u16 f2b(float f){
  union { float f; unsigned int i; } c; c.f = f;
  unsigned int x = c.i;
  return (u16)((x + 0x7FFFu + ((x >> 16) & 1u)) >> 16);   // RNE
}
// flag-aware external load: isbf=1 -> data is bf16, else fp32
__device__ __forceinline__ float ldf(const void* p, size_t i, int isbf){
  return isbf ? b2f(((const u16*)p)[i]) : ((const float*)p)[i];
}
__device__ __forceinline__ float sel4(float4 v, int h){ return h==0?v.x:(h==1?v.y:(h==2?v.z:v.w)); }
__device__ __forceinline__ float lrelu(float v){ return v>0.f ? v : 0.2f*v; }

__device__ __forceinline__ float4 wave_max4(float4 m){
  #pragma unroll
  for(int o=32;o>0;o>>=1){
    m.x=fmaxf(m.x,__shfl_xor(m.x,o));
    m.y=fmaxf(m.y,__shfl_xor(m.y,o));
    m.z=fmaxf(m.z,__shfl_xor(m.z,o));
    m.w=fmaxf(m.w,__shfl_xor(m.w,o));
  }
  return m;
}
__device__ __forceinline__ float4 wave_sum4(float4 m){
  #pragma unroll
  for(int o=32;o>0;o>>=1){
    m.x+=__shfl_xor(m.x,o);
    m.y+=__shfl_xor(m.y,o);
    m.z+=__shfl_xor(m.z,o);
    m.w+=__shfl_xor(m.w,o);
  }
  return m;
}

// ---------------- dtype detection ----------------
// If x is bf16 of N(0,1) data, every 16-bit word has exponent field <= ~130.
// If x is fp32, odd/even words include mantissa halves with uniform-random
// exponent bits -> many words with exponent >= 140. One block, 256 threads.
__global__ void k_detect(const u16* __restrict__ x, int nelem, int* __restrict__ flag){
  __shared__ int bad;
  if (threadIdx.x==0) bad = 0;
  __syncthreads();
  int n = nelem < 8192 ? nelem : 8192;
  int localbad = 0;
  for (int i=threadIdx.x; i<n; i+=256){
    int e = (x[i] >> 7) & 0xFF;
    if (e >= 140) localbad++;
  }
  if (localbad) atomicAdd(&bad, 1);
  __syncthreads();
  if (threadIdx.x==0) *flag = (bad==0) ? 1 : 0;   // 1 = bf16, 0 = fp32
}

// ---------------- CSR build (edges bucketed by dst) ----------------
__global__ void k_hist(const int* __restrict__ dst, int E, int N, int* __restrict__ deg){
  int e = blockIdx.x*256 + threadIdx.x;
  if (e < E){
    int d = dst[e];
    if ((unsigned)d < (unsigned)N) atomicAdd(&deg[d], 1);
  }
}

__global__ void k_scan1(const int* __restrict__ in, int* __restrict__ out, int* __restrict__ bsums, int n){
  __shared__ int s[256];
  int t = threadIdx.x;
  int i = blockIdx.x*256 + t;
  int v = (i<n)? in[i] : 0;
  s[t]=v; __syncthreads();
  for(int off=1; off<256; off<<=1){
    int tv = (t>=off)? s[t-off] : 0;
    __syncthreads();
    s[t]+=tv; __syncthreads();
  }
  if (i<n) out[i] = s[t]-v;            // exclusive
  if (t==255) bsums[blockIdx.x] = s[255];
}

__global__ void k_scan2(int* __restrict__ bsums, int nb){
  __shared__ int s[256];
  int t=threadIdx.x;
  int v=(t<nb)? bsums[t]:0;
  s[t]=v; __syncthreads();
  for(int off=1; off<256; off<<=1){
    int tv=(t>=off)? s[t-off]:0;
    __syncthreads();
    s[t]+=tv; __syncthreads();
  }
  if (t<nb) bsums[t]=s[t]-v;
}

__global__ void k_scan3(int* __restrict__ out, const int* __restrict__ bsums, int n){
  int i = blockIdx.x*256+threadIdx.x;
  if (i<n) out[i]+=bsums[blockIdx.x];
}

__global__ void k_scatter(const int* __restrict__ src, const int* __restrict__ dst,
                          const void* __restrict__ ew, int E, int N,
                          const int* __restrict__ rowptr, int* __restrict__ cursor,
                          int* __restrict__ esrc, float* __restrict__ eewf,
                          const int* __restrict__ flagp){
  int e = blockIdx.x*256+threadIdx.x;
  if (e>=E) return;
  int bf = *flagp;
  int d = dst[e];
  if ((unsigned)d >= (unsigned)N) return;
  int p = rowptr[d] + atomicAdd(&cursor[d],1);
  int s = src[e];
  if ((unsigned)s >= (unsigned)N) s = 0;
  esrc[p] = s;
  eewf[p] = ldf(ew, e, bf);
}

// ---------------- tiled GEMM, C(bf16) = A(MxK) * B(KxN) ----------------
// A: external (dtype per flag) if a_ext, else internal bf16. B: external.
__global__ __launch_bounds__(256) void k_gemm(const void* __restrict__ A, int a_ext,
                                              const void* __restrict__ B,
                                              u16* __restrict__ C, int M, int K, int NC,
                                              const int* __restrict__ flagp){
  __shared__ float As[16][65];
  __shared__ float Bs[16][64];
  int bf = *flagp;
  int a_bf = a_ext ? bf : 1;
  int tid = threadIdx.x;
  int tx = tid & 15, ty = tid >> 4;
  int row0 = blockIdx.y*64, col0 = blockIdx.x*64;
  float acc[4][4] = {};
  for (int k0=0;k0<K;k0+=16){
    #pragma unroll
    for (int i=0;i<4;i++){
      int idx = tid + i*256;
      int r = idx >> 4, c = idx & 15;
      int gr = row0 + r;
      As[c][r] = (gr<M) ? ldf(A, (size_t)gr*K + k0 + c, a_bf) : 0.f;
    }
    #pragma unroll
    for (int i=0;i<4;i++){
      int idx = tid + i*256;
      int r = idx >> 6, c = idx & 63;
      Bs[r][c] = ldf(B, (size_t)(k0+r)*NC + col0 + c, bf);
    }
    __syncthreads();
    #pragma unroll
    for (int kk=0;kk<16;kk++){
      float a[4];
      #pragma unroll
      for (int i=0;i<4;i++) a[i]=As[kk][ty*4+i];
      float4 bv = *(float4*)&Bs[kk][tx*4];
      #pragma unroll
      for (int i=0;i<4;i++){
        acc[i][0]+=a[i]*bv.x; acc[i][1]+=a[i]*bv.y;
        acc[i][2]+=a[i]*bv.z; acc[i][3]+=a[i]*bv.w;
      }
    }
    __syncthreads();
  }
  #pragma unroll
  for (int i=0;i<4;i++){
    int r = row0 + ty*4 + i;
    if (r<M){
      ushort4 o;
      o.x=f2b(acc[i][0]); o.y=f2b(acc[i][1]); o.z=f2b(acc[i][2]); o.w=f2b(acc[i][3]);
      *(ushort4*)&C[(size_t)r*NC + col0 + tx*4] = o;
    }
  }
}

// ---------------- per-node attention coefficients ----------------
__global__ __launch_bounds__(256) void k_att(const u16* __restrict__ xs, const void* __restrict__ att_s,
    const void* __restrict__ att_d, float* __restrict__ a_s, float* __restrict__ a_d, int N,
    const int* __restrict__ flagp){
  int bf = *flagp;
  int n = blockIdx.x;
  int t = threadIdx.x;
  float v = b2f(xs[(size_t)n*HC + t]);
  float ps = v*ldf(att_s, t, bf);
  float pd = v*ldf(att_d, t, bf);
  for(int o=32;o>0;o>>=1){ ps+=__shfl_xor(ps,o); pd+=__shfl_xor(pd,o); }
  if ((t&63)==0){ int h=t>>6; a_s[(size_t)n*4+h]=ps; a_d[(size_t)n*4+h]=pd; }
}

// ce[h] = sum_c We[h*C+c]*att_e[h*C+c]
__global__ void k_ce(const void* __restrict__ We, const void* __restrict__ att_e,
                     float* __restrict__ ce, const int* __restrict__ flagp){
  int bf = *flagp;
  int t=threadIdx.x;
  float p = ldf(We, t, bf)*ldf(att_e, t, bf);
  for(int o=32;o>0;o>>=1) p+=__shfl_xor(p,o);
  if((t&63)==0) ce[t>>6]=p;
}

// ---------------- fused per-node segment softmax + weighted aggregation ----------------
// one wave per destination node
__global__ __launch_bounds__(256) void k_soft_agg(
    const u16* __restrict__ xs, const int* __restrict__ rowptr, const int* __restrict__ deg,
    const int* __restrict__ esrc, const float* __restrict__ eewf,
    const float* __restrict__ a_s, const float* __restrict__ a_d, const float* __restrict__ ce4,
    u16* __restrict__ aggout, int N){
  __shared__ float exbuf[4][MAXD*4];
  int lane = threadIdx.x & 63;
  int w = threadIdx.x >> 6;
  int n = (blockIdx.x<<2) + w;
  if (n >= N) return;
  int row = rowptr[n];
  int dg = deg[n];
  float4 ad = *(const float4*)&a_d[(size_t)n*4];
  float4 ce = *(const float4*)ce4;
  int h = lane >> 4;
  float4 acc = make_float4(0.f,0.f,0.f,0.f);
  if (dg > 0){
    float4 m = make_float4(-1e30f,-1e30f,-1e30f,-1e30f);
    if (dg <= MAXD){
      for (int p=lane; p<dg; p+=64){
        int pos = row+p;
        int s = esrc[pos];
        if ((unsigned)s >= (unsigned)N) s = 0;
        float wv = eewf[pos];
        float4 as = *(const float4*)&a_s[(size_t)s*4];
        float4 ar;
        ar.x = lrelu(as.x+ad.x+wv*ce.x);
        ar.y = lrelu(as.y+ad.y+wv*ce.y);
        ar.z = lrelu(as.z+ad.z+wv*ce.z);
        ar.w = lrelu(as.w+ad.w+wv*ce.w);
        *(float4*)&exbuf[w][p*4] = ar;
        m.x=fmaxf(m.x,ar.x); m.y=fmaxf(m.y,ar.y); m.z=fmaxf(m.z,ar.z); m.w=fmaxf(m.w,ar.w);
      }
      m = wave_max4(m);
      float4 ss = make_float4(0.f,0.f,0.f,0.f);
      for (int p=lane;p<dg;p+=64){
        float4 ar = *(float4*)&exbuf[w][p*4];
        float4 ex;
        ex.x=__expf(ar.x-m.x); ex.y=__expf(ar.y-m.y);
        ex.z=__expf(ar.z-m.z); ex.w=__expf(ar.w-m.w);
        *(float4*)&exbuf[w][p*4] = ex;
        ss.x+=ex.x; ss.y+=ex.y; ss.z+=ex.z; ss.w+=ex.w;
      }
      ss = wave_sum4(ss);
      float4 rcp;
      rcp.x=1.f/(ss.x+1e-16f); rcp.y=1.f/(ss.y+1e-16f);
      rcp.z=1.f/(ss.z+1e-16f); rcp.w=1.f/(ss.w+1e-16f);
      float rsel = sel4(rcp,h);
      for (int e=0;e<dg;e++){
        int pos = row+e;
        int s = esrc[pos];
        if ((unsigned)s >= (unsigned)N) s = 0;
        float wgt = exbuf[w][e*4+h]*rsel;
        ushort4 xv4 = *(const ushort4*)&xs[(size_t)s*HC + lane*4];
        acc.x+=wgt*b2f(xv4.x); acc.y+=wgt*b2f(xv4.y);
        acc.z+=wgt*b2f(xv4.z); acc.w+=wgt*b2f(xv4.w);
      }
    } else {
      // rare fallback: recompute alpha instead of storing
      for (int p=lane;p<dg;p+=64){
        int pos = row+p;
        int s = esrc[pos];
        if ((unsigned)s >= (unsigned)N) s = 0;
        float wv = eewf[pos];
        float4 as = *(const float4*)&a_s[(size_t)s*4];
        m.x=fmaxf(m.x, lrelu(as.x+ad.x+wv*ce.x));
        m.y=fmaxf(m.y, lrelu(as.y+ad.y+wv*ce.y));
        m.z=fmaxf(m.z, lrelu(as.z+ad.z+wv*ce.z));
        m.w=fmaxf(m.w, lrelu(as.w+ad.w+wv*ce.w));
      }
      m = wave_max4(m);
      float4 ss = make_float4(0.f,0.f,0.f,0.f);
      for (int p=lane;p<dg;p+=64){
        int pos = row+p;
        int s = esrc[pos];
        if ((unsigned)s >= (unsigned)N) s = 0;
        float wv = eewf[pos];
        float4 as = *(const float4*)&a_s[(size_t)s*4];
        ss.x+=__expf(lrelu(as.x+ad.x+wv*ce.x)-m.x);
        ss.y+=__expf(lrelu(as.y+ad.y+wv*ce.y)-m.y);
        ss.z+=__expf(lrelu(as.z+ad.z+wv*ce.z)-m.z);
        ss.w+=__expf(lrelu(as.w+ad.w+wv*ce.w)-m.w);
      }
      ss = wave_sum4(ss);
      float4 rcp;
      rcp.x=1.f/(ss.x+1e-16f); rcp.y=1.f/(ss.y+1e-16f);
      rcp.z=1.f/(ss.z+1e-16f); rcp.w=1.f/(ss.w+1e-16f);
      float rsel=sel4(rcp,h), mh=sel4(m,h), adh=sel4(ad,h), ceh=sel4(ce,h);
      for (int e=0;e<dg;e++){
        int pos=row+e;
        int s=esrc[pos];
        if ((unsigned)s >= (unsigned)N) s = 0;
        float wv=eewf[pos];
        float ar = lrelu(a_s[(size_t)s*4+h]+adh+wv*ceh);
        float wgt = __expf(ar-mh)*rsel;
        ushort4 xv4 = *(const ushort4*)&xs[(size_t)s*HC + lane*4];
        acc.x+=wgt*b2f(xv4.x); acc.y+=wgt*b2f(xv4.y);
        acc.z+=wgt*b2f(xv4.z); acc.w+=wgt*b2f(xv4.w);
      }
    }
  }
  ushort4 o;
  o.x=f2b(acc.x); o.y=f2b(acc.y); o.z=f2b(acc.z); o.w=f2b(acc.w);
  *(ushort4*)&aggout[(size_t)n*HC + lane*4] = o;
}

// layer-1 epilogue: h = relu(l2norm(agg + b1)), in place; one wave per node
__global__ __launch_bounds__(256) void k_norm(u16* __restrict__ agg, const void* __restrict__ b, int N,
                                              const int* __restrict__ flagp){
  int bf = *flagp;
  int lane = threadIdx.x & 63;
  int n = (blockIdx.x*256+threadIdx.x)>>6;
  if (n>=N) return;
  ushort4 u = *(ushort4*)&agg[(size_t)n*HC + lane*4];
  float4 v;
  v.x = b2f(u.x) + ldf(b, lane*4+0, bf);
  v.y = b2f(u.y) + ldf(b, lane*4+1, bf);
  v.z = b2f(u.z) + ldf(b, lane*4+2, bf);
  v.w = b2f(u.w) + ldf(b, lane*4+3, bf);
  float ss = v.x*v.x+v.y*v.y+v.z*v.z+v.w*v.w;
  for(int o=32;o>0;o>>=1) ss += __shfl_xor(ss,o);
  float inv = 1.f/fmaxf(sqrtf(ss), 1e-12f);
  ushort4 o4;
  o4.x = f2b(fmaxf(v.x*inv,0.f)); o4.y = f2b(fmaxf(v.y*inv,0.f));
  o4.z = f2b(fmaxf(v.z*inv,0.f)); o4.w = f2b(fmaxf(v.w*inv,0.f));
  *(ushort4*)&agg[(size_t)n*HC + lane*4] = o4;
}

// layer-2 epilogue: mean over heads + b2, write output in detected dtype
__global__ void k_final(const u16* __restrict__ agg, const void* __restrict__ b2,
                        void* __restrict__ out, int N, const int* __restrict__ flagp){
  int bf = *flagp;
  int i = blockIdx.x*256+threadIdx.x;
  if (i >= N*CDIM) return;
  int n = i>>6, c = i&63;
  const u16* r = &agg[(size_t)n*HC];
  float s = b2f(r[c])+b2f(r[c+64])+b2f(r[c+128])+b2f(r[c+192]);
  float v = 0.25f*s + ldf(b2, c, bf);
  if (bf) ((u16*)out)[i] = f2b(v);
  else    ((float*)out)[i] = v;
}

extern "C" void kernel_launch(void* const* d_in, const int* in_sizes, int n_in,
                              void* d_out, int out_size, void* d_ws, size_t ws_size,
                              hipStream_t stream){
  const void* x_in = d_in[0];
  const int* eidx  = (const int*)d_in[1];
  const void* ew   = d_in[2];
  const void* W1   = d_in[3];
  const void* as1  = d_in[4];
  const void* ad1  = d_in[5];
  const void* We1  = d_in[6];
  const void* ae1  = d_in[7];
  const void* b1   = d_in[8];
  const void* W2   = d_in[9];
  const void* as2  = d_in[10];
  const void* ad2  = d_in[11];
  const void* We2  = d_in[12];
  const void* ae2  = d_in[13];
  const void* b2   = d_in[14];

  int N = in_sizes[0]/128;
  int E = in_sizes[2];
  const int* src = eidx;
  const int* dst = eidx + E;

  char* w = (char*)d_ws;
  auto alloc = [&](size_t bytes)->char*{ char* p=w; w += (bytes+255)/256*256; return p; };
  int*   flag  = (int*)alloc(256);
  u16*   xs    = (u16*)alloc((size_t)N*HC*2);   // bf16 feature buffer A (25.6 MB)
  u16*   agg   = (u16*)alloc((size_t)N*HC*2);   // bf16 feature buffer B (25.6 MB)
  float* a_s   = (float*)alloc((size_t)N*4*4);
  float* a_d   = (float*)alloc((size_t)N*4*4);
  int*   deg   = (int*)alloc((size_t)N*4);
  int*   cursor= (int*)alloc((size_t)N*4);
  int*   rowptr= (int*)alloc((size_t)N*4);
  int*   bsums = (int*)alloc(256*4);
  int*   esrc  = (int*)alloc((size_t)E*4);
  float* eewf  = (float*)alloc((size_t)E*4);
  float* ce    = (float*)alloc(64);

  hipMemsetAsync(deg, 0, (size_t)N*4, stream);
  hipMemsetAsync(cursor, 0, (size_t)N*4, stream);

  k_detect<<<1,256,0,stream>>>((const u16*)x_in, in_sizes[0], flag);

  int eb = (E+255)/256;
  int nb = (N+255)/256;
  k_hist<<<eb,256,0,stream>>>(dst, E, N, deg);
  k_scan1<<<nb,256,0,stream>>>(deg, rowptr, bsums, N);
  k_scan2<<<1,256,0,stream>>>(bsums, nb);
  k_scan3<<<nb,256,0,stream>>>(rowptr, bsums, N);
  k_scatter<<<eb,256,0,stream>>>(src, dst, ew, E, N, rowptr, cursor, esrc, eewf, flag);

  dim3 gemmGrid(HC/64, (N+63)/64);
  int nwb = (N+3)/4;   // 4 node-waves per block

  // ---- layer 1 ----
  k_gemm<<<gemmGrid,256,0,stream>>>(x_in, 1, W1, xs, N, 128, HC, flag);
  k_att<<<N,256,0,stream>>>(xs, as1, ad1, a_s, a_d, N, flag);
  k_ce<<<1,256,0,stream>>>(We1, ae1, ce, flag);
  k_soft_agg<<<nwb,256,0,stream>>>(xs, rowptr, deg, esrc, eewf, a_s, a_d, ce, agg, N);
  k_norm<<<nwb,256,0,stream>>>(agg, b1, N, flag);

  // ---- layer 2 ----
  k_gemm<<<gemmGrid,256,0,stream>>>(agg, 0, W2, xs, N, HC, HC, flag);
  k_att<<<N,256,0,stream>>>(xs, as2, ad2, a_s, a_d, N, flag);
  k_ce<<<1,256,0,stream>>>(We2, ae2, ce, flag);
  k_soft_agg<<<nwb,256,0,stream>>>(xs, rowptr, deg, esrc, eewf, a_s, a_d, ce, agg, N);
  k_final<<<(N*CDIM+255)/256,256,0,stream>>>(agg, b2, d_out, N, flag);
}

// Round 4
// 472.867 us; speedup vs baseline: 1.4282x; 1.4282x over previous
//
#include <hip/hip_runtime.h>
#include <hip/hip_bf16.h>

typedef unsigned short u16;
using bf16x8 = __attribute__((ext_vector_type(8))) short;
using f32x4v = __attribute__((ext_vector_type(4))) float;

#define HC 256     // H*C
#define CDIM 64
#define MAXD 512   // per-wave LDS softmax buffer capacity (edges per node)

__device__ __forceinline__ float b2f(u16 u){
  union { unsigned int i; float f; } c; c.i = ((unsigned)u) << 16; return c.f;
}
__device__ __forceinline__ u16 f2b(float f){
  union { float f; unsigned int i; } c; c.f = f;
  unsigned int x = c.i;
  return (u16)((x + 0x7FFFu + ((x >> 16) & 1u)) >> 16);   // RNE
}
// flag-aware external load: isbf=1 -> data is bf16, else fp32
__device__ __forceinline__ float ldf(const void* p, size_t i, int isbf){
  return isbf ? b2f(((const u16*)p)[i]) : ((const float*)p)[i];
}
__device__ __forceinline__ float sel4(float4 v, int h){ return h==0?v.x:(h==1?v.y:(h==2?v.z:v.w)); }
__device__ __forceinline__ float lrelu(float v){ return v>0.f ? v : 0.2f*v; }

__device__ __forceinline__ float4 wave_max4(float4 m){
  #pragma unroll
  for(int o=32;o>0;o>>=1){
    m.x=fmaxf(m.x,__shfl_xor(m.x,o));
    m.y=fmaxf(m.y,__shfl_xor(m.y,o));
    m.z=fmaxf(m.z,__shfl_xor(m.z,o));
    m.w=fmaxf(m.w,__shfl_xor(m.w,o));
  }
  return m;
}
__device__ __forceinline__ float4 wave_sum4(float4 m){
  #pragma unroll
  for(int o=32;o>0;o>>=1){
    m.x+=__shfl_xor(m.x,o);
    m.y+=__shfl_xor(m.y,o);
    m.z+=__shfl_xor(m.z,o);
    m.w+=__shfl_xor(m.w,o);
  }
  return m;
}

// ---------------- dtype detection (1 = bf16, 0 = fp32) ----------------
__global__ void k_detect(const u16* __restrict__ x, int nelem, int* __restrict__ flag){
  __shared__ int bad;
  if (threadIdx.x==0) bad = 0;
  __syncthreads();
  int n = nelem < 8192 ? nelem : 8192;
  int localbad = 0;
  for (int i=threadIdx.x; i<n; i+=256){
    int e = (x[i] >> 7) & 0xFF;
    if (e >= 140) localbad++;
  }
  if (localbad) atomicAdd(&bad, 1);
  __syncthreads();
  if (threadIdx.x==0) *flag = (bad==0) ? 1 : 0;
}

// ---------------- CSR build (edges bucketed by dst) ----------------
__global__ void k_hist(const int* __restrict__ dst, int E, int N, int* __restrict__ deg){
  int e = blockIdx.x*256 + threadIdx.x;
  if (e < E){
    int d = dst[e];
    if ((unsigned)d < (unsigned)N) atomicAdd(&deg[d], 1);
  }
}

__global__ void k_scan1(const int* __restrict__ in, int* __restrict__ out, int* __restrict__ bsums, int n){
  __shared__ int s[256];
  int t = threadIdx.x;
  int i = blockIdx.x*256 + t;
  int v = (i<n)? in[i] : 0;
  s[t]=v; __syncthreads();
  for(int off=1; off<256; off<<=1){
    int tv = (t>=off)? s[t-off] : 0;
    __syncthreads();
    s[t]+=tv; __syncthreads();
  }
  if (i<n) out[i] = s[t]-v;            // exclusive
  if (t==255) bsums[blockIdx.x] = s[255];
}

__global__ void k_scan2(int* __restrict__ bsums, int nb){
  __shared__ int s[256];
  int t=threadIdx.x;
  int v=(t<nb)? bsums[t]:0;
  s[t]=v; __syncthreads();
  for(int off=1; off<256; off<<=1){
    int tv=(t>=off)? s[t-off]:0;
    __syncthreads();
    s[t]+=tv; __syncthreads();
  }
  if (t<nb) bsums[t]=s[t]-v;
}

__global__ void k_scan3(int* __restrict__ out, const int* __restrict__ bsums, int n){
  int i = blockIdx.x*256+threadIdx.x;
  if (i<n) out[i]+=bsums[blockIdx.x];
}

__global__ void k_scatter(const int* __restrict__ src, const int* __restrict__ dst,
                          const void* __restrict__ ew, int E, int N,
                          const int* __restrict__ rowptr, int* __restrict__ cursor,
                          int* __restrict__ esrc, float* __restrict__ eewf,
                          const int* __restrict__ flagp){
  int e = blockIdx.x*256+threadIdx.x;
  if (e>=E) return;
  int bf = *flagp;
  int d = dst[e];
  if ((unsigned)d >= (unsigned)N) return;
  int p = rowptr[d] + atomicAdd(&cursor[d],1);
  int s = src[e];
  if ((unsigned)s >= (unsigned)N) s = 0;
  esrc[p] = s;
  eewf[p] = ldf(ew, e, bf);
}

// ---------------- weight prep: Bt[n][k] = bf16(W[k][n]) ----------------
__global__ void k_prepB(const void* __restrict__ W, u16* __restrict__ Bt, int K,
                        const int* __restrict__ flagp){
  int bf = *flagp;
  int k = blockIdx.x, t = threadIdx.x;
  float v = ldf(W, (size_t)k*HC + t, bf);
  Bt[(size_t)t*K + k] = f2b(v);
}

// ---------------- MFMA GEMM: C[m][0:256] = A[m][:]*B, tile 64x256, BK=32 ----------------
// Also computes per-row attention dots a_s/a_d in the epilogue.
__global__ __launch_bounds__(256) void k_gemm_mfma(
    const void* __restrict__ A, int a_ext, const u16* __restrict__ Bt,
    u16* __restrict__ C, const void* __restrict__ att_s, const void* __restrict__ att_d,
    float* __restrict__ a_s, float* __restrict__ a_d,
    int M, int K, const int* __restrict__ flagp)
{
  __shared__ u16 sh[64*264];           // 33 KB; K-loop: [As 2048][Bs 8192]; epilogue: 64x264 C tile
  u16* As = sh;
  u16* Bs = sh + 2048;
  int bf = *flagp;
  int a_bf = a_ext ? bf : 1;
  int tid = threadIdx.x;
  int lane = tid & 63, w = tid >> 6;
  int quad = lane >> 4, ln = lane & 15;
  int m0 = blockIdx.x * 64;

  f32x4v acc[4][4] = {};
  for (int k0 = 0; k0 < K; k0 += 32){
    // stage A tile 64x32 (convert to bf16 if needed)
    {
      int m = tid >> 2, g = tid & 3;
      int r = m0 + m;
      uint4 pack;
      if (r < M){
        size_t base = (size_t)r*K + k0 + g*8;
        if (a_bf){
          pack = *(const uint4*)((const u16*)A + base);
        } else {
          const float* Af = (const float*)A + base;
          float4 f0 = *(const float4*)Af;
          float4 f1 = *(const float4*)(Af+4);
          unsigned a0 = (unsigned)f2b(f0.x) | ((unsigned)f2b(f0.y)<<16);
          unsigned a1 = (unsigned)f2b(f0.z) | ((unsigned)f2b(f0.w)<<16);
          unsigned a2 = (unsigned)f2b(f1.x) | ((unsigned)f2b(f1.y)<<16);
          unsigned a3 = (unsigned)f2b(f1.z) | ((unsigned)f2b(f1.w)<<16);
          pack = make_uint4(a0,a1,a2,a3);
        }
      } else pack = make_uint4(0,0,0,0);
      ((uint4*)As)[tid] = pack;
    }
    // stage B tile 256x32 (already bf16, [n][k] layout)
    #pragma unroll
    for (int i=0;i<4;i++){
      int n = i*64 + (tid>>2), g = tid&3;
      ((uint4*)Bs)[i*256 + tid] = *(const uint4*)(Bt + (size_t)n*K + k0 + g*8);
    }
    __syncthreads();
    bf16x8 af[4], bfr[4];
    #pragma unroll
    for (int mi=0;mi<4;mi++) af[mi] = *(const bf16x8*)&As[(mi*16+ln)*32 + quad*8];
    #pragma unroll
    for (int nj=0;nj<4;nj++) bfr[nj] = *(const bf16x8*)&Bs[((size_t)w*64+nj*16+ln)*32 + quad*8];
    #pragma unroll
    for (int mi=0;mi<4;mi++)
      #pragma unroll
      for (int nj=0;nj<4;nj++)
        acc[mi][nj] = __builtin_amdgcn_mfma_f32_16x16x32_bf16(af[mi], bfr[nj], acc[mi][nj], 0,0,0);
    __syncthreads();
  }
  // dump accumulators to LDS (C/D layout: row=quad*4+reg, col=lane&15)
  #pragma unroll
  for (int mi=0;mi<4;mi++)
    #pragma unroll
    for (int nj=0;nj<4;nj++)
      #pragma unroll
      for (int r=0;r<4;r++)
        sh[(mi*16 + quad*4 + r)*264 + w*64 + nj*16 + ln] = f2b(acc[mi][nj][r]);
  __syncthreads();
  // coalesced bulk store of the 64x256 bf16 tile
  #pragma unroll
  for (int j=0;j<8;j++){
    int idx = j*256 + tid;
    int r = idx >> 5, gq = idx & 31;
    if (m0 + r < M)
      *(uint4*)(C + (size_t)(m0+r)*HC + gq*8) = *(const uint4*)&sh[r*264 + gq*8];
  }
  // per-row attention dots: wave w handles rows w*16..w*16+15
  float4 sv, dv;
  sv.x=ldf(att_s,lane*4+0,bf); sv.y=ldf(att_s,lane*4+1,bf);
  sv.z=ldf(att_s,lane*4+2,bf); sv.w=ldf(att_s,lane*4+3,bf);
  dv.x=ldf(att_d,lane*4+0,bf); dv.y=ldf(att_d,lane*4+1,bf);
  dv.z=ldf(att_d,lane*4+2,bf); dv.w=ldf(att_d,lane*4+3,bf);
  for (int rr=0; rr<16; rr++){
    int r = w*16 + rr;
    ushort4 u = *(const ushort4*)&sh[r*264 + lane*4];
    float ps = b2f(u.x)*sv.x + b2f(u.y)*sv.y + b2f(u.z)*sv.z + b2f(u.w)*sv.w;
    float pd = b2f(u.x)*dv.x + b2f(u.y)*dv.y + b2f(u.z)*dv.z + b2f(u.w)*dv.w;
    #pragma unroll
    for (int o=1;o<16;o<<=1){ ps+=__shfl_xor(ps,o); pd+=__shfl_xor(pd,o); }
    if ((lane&15)==0 && m0+r<M){
      a_s[(size_t)(m0+r)*4 + (lane>>4)] = ps;
      a_d[(size_t)(m0+r)*4 + (lane>>4)] = pd;
    }
  }
}

// ce[h] = sum_c We[h*C+c]*att_e[h*C+c]
__global__ void k_ce(const void* __restrict__ We, const void* __restrict__ att_e,
                     float* __restrict__ ce, const int* __restrict__ flagp){
  int bf = *flagp;
  int t=threadIdx.x;
  float p = ldf(We, t, bf)*ldf(att_e, t, bf);
  for(int o=32;o>0;o>>=1) p+=__shfl_xor(p,o);
  if((t&63)==0) ce[t>>6]=p;
}

// ---------------- fused segment softmax + aggregation + layer epilogue ----------------
// one wave per destination node. layer==1: +bias, l2norm, relu -> bf16 out (N x 256)
// layer==2: mean over heads + bias -> out (N x 64, dtype per flag)
__global__ __launch_bounds__(256) void k_soft_agg(
    const u16* __restrict__ xs, const int* __restrict__ rowptr, const int* __restrict__ deg,
    const int* __restrict__ esrc, const float* __restrict__ eewf,
    const float* __restrict__ a_s, const float* __restrict__ a_d, const float* __restrict__ ce4,
    const void* __restrict__ bias, void* __restrict__ outp, int N, int layer,
    const int* __restrict__ flagp){
  __shared__ float exbuf[4][MAXD*4];
  int bf = *flagp;
  int lane = threadIdx.x & 63;
  int w = threadIdx.x >> 6;
  int n = (blockIdx.x<<2) + w;
  if (n >= N) return;
  int row = rowptr[n];
  int dg = deg[n];
  float4 ad = *(const float4*)&a_d[(size_t)n*4];
  float4 ce = *(const float4*)ce4;
  int h = lane >> 4;
  float4 acc = make_float4(0.f,0.f,0.f,0.f);
  if (dg > 0){
    float4 m = make_float4(-1e30f,-1e30f,-1e30f,-1e30f);
    if (dg <= MAXD){
      for (int p=lane; p<dg; p+=64){
        int pos = row+p;
        int s = esrc[pos];
        if ((unsigned)s >= (unsigned)N) s = 0;
        float wv = eewf[pos];
        float4 as = *(const float4*)&a_s[(size_t)s*4];
        float4 ar;
        ar.x = lrelu(as.x+ad.x+wv*ce.x);
        ar.y = lrelu(as.y+ad.y+wv*ce.y);
        ar.z = lrelu(as.z+ad.z+wv*ce.z);
        ar.w = lrelu(as.w+ad.w+wv*ce.w);
        *(float4*)&exbuf[w][p*4] = ar;
        m.x=fmaxf(m.x,ar.x); m.y=fmaxf(m.y,ar.y); m.z=fmaxf(m.z,ar.z); m.w=fmaxf(m.w,ar.w);
      }
      m = wave_max4(m);
      float4 ss = make_float4(0.f,0.f,0.f,0.f);
      for (int p=lane;p<dg;p+=64){
        float4 ar = *(float4*)&exbuf[w][p*4];
        float4 ex;
        ex.x=__expf(ar.x-m.x); ex.y=__expf(ar.y-m.y);
        ex.z=__expf(ar.z-m.z); ex.w=__expf(ar.w-m.w);
        *(float4*)&exbuf[w][p*4] = ex;
        ss.x+=ex.x; ss.y+=ex.y; ss.z+=ex.z; ss.w+=ex.w;
      }
      ss = wave_sum4(ss);
      float4 rcp;
      rcp.x=1.f/(ss.x+1e-16f); rcp.y=1.f/(ss.y+1e-16f);
      rcp.z=1.f/(ss.z+1e-16f); rcp.w=1.f/(ss.w+1e-16f);
      float rsel = sel4(rcp,h);
      for (int e=0;e<dg;e++){
        int pos = row+e;
        int s = esrc[pos];
        if ((unsigned)s >= (unsigned)N) s = 0;
        float wgt = exbuf[w][e*4+h]*rsel;
        ushort4 xv4 = *(const ushort4*)&xs[(size_t)s*HC + lane*4];
        acc.x+=wgt*b2f(xv4.x); acc.y+=wgt*b2f(xv4.y);
        acc.z+=wgt*b2f(xv4.z); acc.w+=wgt*b2f(xv4.w);
      }
    } else {
      for (int p=lane;p<dg;p+=64){
        int pos = row+p;
        int s = esrc[pos];
        if ((unsigned)s >= (unsigned)N) s = 0;
        float wv = eewf[pos];
        float4 as = *(const float4*)&a_s[(size_t)s*4];
        m.x=fmaxf(m.x, lrelu(as.x+ad.x+wv*ce.x));
        m.y=fmaxf(m.y, lrelu(as.y+ad.y+wv*ce.y));
        m.z=fmaxf(m.z, lrelu(as.z+ad.z+wv*ce.z));
        m.w=fmaxf(m.w, lrelu(as.w+ad.w+wv*ce.w));
      }
      m = wave_max4(m);
      float4 ss = make_float4(0.f,0.f,0.f,0.f);
      for (int p=lane;p<dg;p+=64){
        int pos = row+p;
        int s = esrc[pos];
        if ((unsigned)s >= (unsigned)N) s = 0;
        float wv = eewf[pos];
        float4 as = *(const float4*)&a_s[(size_t)s*4];
        ss.x+=__expf(lrelu(as.x+ad.x+wv*ce.x)-m.x);
        ss.y+=__expf(lrelu(as.y+ad.y+wv*ce.y)-m.y);
        ss.z+=__expf(lrelu(as.z+ad.z+wv*ce.z)-m.z);
        ss.w+=__expf(lrelu(as.w+ad.w+wv*ce.w)-m.w);
      }
      ss = wave_sum4(ss);
      float4 rcp;
      rcp.x=1.f/(ss.x+1e-16f); rcp.y=1.f/(ss.y+1e-16f);
      rcp.z=1.f/(ss.z+1e-16f); rcp.w=1.f/(ss.w+1e-16f);
      float rsel=sel4(rcp,h), mh=sel4(m,h), adh=sel4(ad,h), ceh=sel4(ce,h);
      for (int e=0;e<dg;e++){
        int pos=row+e;
        int s=esrc[pos];
        if ((unsigned)s >= (unsigned)N) s = 0;
        float wv=eewf[pos];
        float ar = lrelu(a_s[(size_t)s*4+h]+adh+wv*ceh);
        float wgt = __expf(ar-mh)*rsel;
        ushort4 xv4 = *(const ushort4*)&xs[(size_t)s*HC + lane*4];
        acc.x+=wgt*b2f(xv4.x); acc.y+=wgt*b2f(xv4.y);
        acc.z+=wgt*b2f(xv4.z); acc.w+=wgt*b2f(xv4.w);
      }
    }
  }
  if (layer==1){
    // h = relu(l2norm(acc + b1)) -> bf16
    float4 v;
    v.x = acc.x + ldf(bias, lane*4+0, bf);
    v.y = acc.y + ldf(bias, lane*4+1, bf);
    v.z = acc.z + ldf(bias, lane*4+2, bf);
    v.w = acc.w + ldf(bias, lane*4+3, bf);
    float ss = v.x*v.x+v.y*v.y+v.z*v.z+v.w*v.w;
    #pragma unroll
    for(int o=32;o>0;o>>=1) ss += __shfl_xor(ss,o);
    float inv = 1.f/fmaxf(sqrtf(ss), 1e-12f);
    ushort4 o4;
    o4.x = f2b(fmaxf(v.x*inv,0.f)); o4.y = f2b(fmaxf(v.y*inv,0.f));
    o4.z = f2b(fmaxf(v.z*inv,0.f)); o4.w = f2b(fmaxf(v.w*inv,0.f));
    *(ushort4*)((u16*)outp + (size_t)n*HC + lane*4) = o4;
  } else {
    // mean over heads + b2 -> final output
    float4 s = acc;
    #pragma unroll
    for (int o=16;o<=32;o<<=1){
      s.x+=__shfl_xor(s.x,o); s.y+=__shfl_xor(s.y,o);
      s.z+=__shfl_xor(s.z,o); s.w+=__shfl_xor(s.w,o);
    }
    if (lane < 16){
      float4 v;
      v.x = 0.25f*s.x + ldf(bias, lane*4+0, bf);
      v.y = 0.25f*s.y + ldf(bias, lane*4+1, bf);
      v.z = 0.25f*s.z + ldf(bias, lane*4+2, bf);
      v.w = 0.25f*s.w + ldf(bias, lane*4+3, bf);
      if (bf){
        ushort4 o4; o4.x=f2b(v.x); o4.y=f2b(v.y); o4.z=f2b(v.z); o4.w=f2b(v.w);
        *(ushort4*)((u16*)outp + (size_t)n*CDIM + lane*4) = o4;
      } else {
        *(float4*)((float*)outp + (size_t)n*CDIM + lane*4) = v;
      }
    }
  }
}

extern "C" void kernel_launch(void* const* d_in, const int* in_sizes, int n_in,
                              void* d_out, int out_size, void* d_ws, size_t ws_size,
                              hipStream_t stream){
  const void* x_in = d_in[0];
  const int* eidx  = (const int*)d_in[1];
  const void* ew   = d_in[2];
  const void* W1   = d_in[3];
  const void* as1  = d_in[4];
  const void* ad1  = d_in[5];
  const void* We1  = d_in[6];
  const void* ae1  = d_in[7];
  const void* b1   = d_in[8];
  const void* W2   = d_in[9];
  const void* as2  = d_in[10];
  const void* ad2  = d_in[11];
  const void* We2  = d_in[12];
  const void* ae2  = d_in[13];
  const void* b2   = d_in[14];

  int N = in_sizes[0]/128;
  int E = in_sizes[2];
  const int* src = eidx;
  const int* dst = eidx + E;

  char* w = (char*)d_ws;
  auto alloc = [&](size_t bytes)->char*{ char* p=w; w += (bytes+255)/256*256; return p; };
  int*   flag  = (int*)alloc(256);
  u16*   xs    = (u16*)alloc((size_t)N*HC*2);   // bf16 feature buffer A
  u16*   agg   = (u16*)alloc((size_t)N*HC*2);   // bf16 feature buffer B (h)
  float* a_s   = (float*)alloc((size_t)N*4*4);
  float* a_d   = (float*)alloc((size_t)N*4*4);
  int*   deg   = (int*)alloc((size_t)N*4);
  int*   cursor= (int*)alloc((size_t)N*4);
  int*   rowptr= (int*)alloc((size_t)N*4);
  int*   bsums = (int*)alloc(256*4);
  int*   esrc  = (int*)alloc((size_t)E*4);
  float* eewf  = (float*)alloc((size_t)E*4);
  float* ce    = (float*)alloc(64);
  u16*   Bt1   = (u16*)alloc((size_t)HC*128*2); // W1^T bf16 [256][128]
  u16*   Bt2   = (u16*)alloc((size_t)HC*HC*2);  // W2^T bf16 [256][256]

  hipMemsetAsync(deg, 0, (size_t)N*4, stream);
  hipMemsetAsync(cursor, 0, (size_t)N*4, stream);

  k_detect<<<1,256,0,stream>>>((const u16*)x_in, in_sizes[0], flag);

  int eb = (E+255)/256;
  int nb = (N+255)/256;
  k_hist<<<eb,256,0,stream>>>(dst, E, N, deg);
  k_scan1<<<nb,256,0,stream>>>(deg, rowptr, bsums, N);
  k_scan2<<<1,256,0,stream>>>(bsums, nb);
  k_scan3<<<nb,256,0,stream>>>(rowptr, bsums, N);
  k_scatter<<<eb,256,0,stream>>>(src, dst, ew, E, N, rowptr, cursor, esrc, eewf, flag);
  k_prepB<<<128,256,0,stream>>>(W1, Bt1, 128, flag);
  k_prepB<<<256,256,0,stream>>>(W2, Bt2, 256, flag);

  int gemmBlocks = (N+63)/64;
  int nwb = (N+3)/4;   // 4 node-waves per block

  // ---- layer 1 ----
  k_gemm_mfma<<<gemmBlocks,256,0,stream>>>(x_in, 1, Bt1, xs, as1, ad1, a_s, a_d, N, 128, flag);
  k_ce<<<1,256,0,stream>>>(We1, ae1, ce, flag);
  k_soft_agg<<<nwb,256,0,stream>>>(xs, rowptr, deg, esrc, eewf, a_s, a_d, ce, b1, agg, N, 1, flag);

  // ---- layer 2 ----
  k_gemm_mfma<<<gemmBlocks,256,0,stream>>>(agg, 0, Bt2, xs, as2, ad2, a_s, a_d, N, 256, flag);
  k_ce<<<1,256,0,stream>>>(We2, ae2, ce, flag);
  k_soft_agg<<<nwb,256,0,stream>>>(xs, rowptr, deg, esrc, eewf, a_s, a_d, ce, b2, d_out, N, 2, flag);
}

// Round 5
// 391.924 us; speedup vs baseline: 1.7232x; 1.2065x over previous
//
#include <hip/hip_runtime.h>
#include <hip/hip_bf16.h>

typedef unsigned short u16;
using bf16x8 = __attribute__((ext_vector_type(8))) short;
using f32x4v = __attribute__((ext_vector_type(4))) float;

#define HC 256     // H*C
#define CDIM 64

__device__ __forceinline__ float b2f(u16 u){
  union { unsigned int i; float f; } c; c.i = ((unsigned)u) << 16; return c.f;
}
__device__ __forceinline__ u16 f2b(float f){
  union { float f; unsigned int i; } c; c.f = f;
  unsigned int x = c.i;
  return (u16)((x + 0x7FFFu + ((x >> 16) & 1u)) >> 16);   // RNE
}
// flag-aware external load: isbf=1 -> data is bf16, else fp32
__device__ __forceinline__ float ldf(const void* p, size_t i, int isbf){
  return isbf ? b2f(((const u16*)p)[i]) : ((const float*)p)[i];
}
__device__ __forceinline__ float sel4(float4 v, int h){ return h==0?v.x:(h==1?v.y:(h==2?v.z:v.w)); }
__device__ __forceinline__ float lrelu(float v){ return v>0.f ? v : 0.2f*v; }

// broadcast lane e's float to all lanes (e wave-uniform)
__device__ __forceinline__ float rdlf(float v, int e){
  return __int_as_float(__builtin_amdgcn_readlane(__float_as_int(v), e));
}
// lane e's per-head weight, selected for this lane's head h
__device__ __forceinline__ float rdl_sel(float4 v, int h, int e){
  float w0 = rdlf(v.x, e), w1 = rdlf(v.y, e), w2 = rdlf(v.z, e), w3 = rdlf(v.w, e);
  return h==0?w0:(h==1?w1:(h==2?w2:w3));
}

__device__ __forceinline__ float4 wave_max4(float4 m){
  #pragma unroll
  for(int o=32;o>0;o>>=1){
    m.x=fmaxf(m.x,__shfl_xor(m.x,o));
    m.y=fmaxf(m.y,__shfl_xor(m.y,o));
    m.z=fmaxf(m.z,__shfl_xor(m.z,o));
    m.w=fmaxf(m.w,__shfl_xor(m.w,o));
  }
  return m;
}
__device__ __forceinline__ float4 wave_sum4(float4 m){
  #pragma unroll
  for(int o=32;o>0;o>>=1){
    m.x+=__shfl_xor(m.x,o);
    m.y+=__shfl_xor(m.y,o);
    m.z+=__shfl_xor(m.z,o);
    m.w+=__shfl_xor(m.w,o);
  }
  return m;
}

// ---------------- dtype detection (1 = bf16, 0 = fp32) ----------------
__global__ void k_detect(const u16* __restrict__ x, int nelem, int* __restrict__ flag){
  __shared__ int bad;
  if (threadIdx.x==0) bad = 0;
  __syncthreads();
  int n = nelem < 8192 ? nelem : 8192;
  int localbad = 0;
  for (int i=threadIdx.x; i<n; i+=256){
    int e = (x[i] >> 7) & 0xFF;
    if (e >= 140) localbad++;
  }
  if (localbad) atomicAdd(&bad, 1);
  __syncthreads();
  if (threadIdx.x==0) *flag = (bad==0) ? 1 : 0;
}

// ---------------- CSR build (edges bucketed by dst) ----------------
__global__ void k_hist(const int* __restrict__ dst, int E, int N, int* __restrict__ deg){
  int e = blockIdx.x*256 + threadIdx.x;
  if (e < E){
    int d = dst[e];
    if ((unsigned)d < (unsigned)N) atomicAdd(&deg[d], 1);
  }
}

__global__ void k_scan1(const int* __restrict__ in, int* __restrict__ out, int* __restrict__ bsums, int n){
  __shared__ int s[256];
  int t = threadIdx.x;
  int i = blockIdx.x*256 + t;
  int v = (i<n)? in[i] : 0;
  s[t]=v; __syncthreads();
  for(int off=1; off<256; off<<=1){
    int tv = (t>=off)? s[t-off] : 0;
    __syncthreads();
    s[t]+=tv; __syncthreads();
  }
  if (i<n) out[i] = s[t]-v;            // exclusive
  if (t==255) bsums[blockIdx.x] = s[255];
}

__global__ void k_scan2(int* __restrict__ bsums, int nb){
  __shared__ int s[256];
  int t=threadIdx.x;
  int v=(t<nb)? bsums[t]:0;
  s[t]=v; __syncthreads();
  for(int off=1; off<256; off<<=1){
    int tv=(t>=off)? s[t-off]:0;
    __syncthreads();
    s[t]+=tv; __syncthreads();
  }
  if (t<nb) bsums[t]=s[t]-v;
}

__global__ void k_scan3(int* __restrict__ out, const int* __restrict__ bsums, int n){
  int i = blockIdx.x*256+threadIdx.x;
  if (i<n) out[i]+=bsums[blockIdx.x];
}

__global__ void k_scatter(const int* __restrict__ src, const int* __restrict__ dst,
                          const void* __restrict__ ew, int E, int N,
                          const int* __restrict__ rowptr, int* __restrict__ cursor,
                          int* __restrict__ esrc, float* __restrict__ eewf,
                          const int* __restrict__ flagp){
  int e = blockIdx.x*256+threadIdx.x;
  if (e>=E) return;
  int bf = *flagp;
  int d = dst[e];
  if ((unsigned)d >= (unsigned)N) return;
  int p = rowptr[d] + atomicAdd(&cursor[d],1);
  int s = src[e];
  if ((unsigned)s >= (unsigned)N) s = 0;
  esrc[p] = s;
  eewf[p] = ldf(ew, e, bf);
}

// ---------------- weight prep: Bt[n][k] = bf16(W[k][n]) ----------------
__global__ void k_prepB(const void* __restrict__ W, u16* __restrict__ Bt, int K,
                        const int* __restrict__ flagp){
  int bf = *flagp;
  int k = blockIdx.x, t = threadIdx.x;
  float v = ldf(W, (size_t)k*HC + t, bf);
  Bt[(size_t)t*K + k] = f2b(v);
}

// ---------------- MFMA GEMM: C[m][0:256] = A[m][:]*B, tile 64x256, BK=32 ----------------
// Also computes per-row attention dots a_s/a_d in the epilogue.
__global__ __launch_bounds__(256) void k_gemm_mfma(
    const void* __restrict__ A, int a_ext, const u16* __restrict__ Bt,
    u16* __restrict__ C, const void* __restrict__ att_s, const void* __restrict__ att_d,
    float* __restrict__ a_s, float* __restrict__ a_d,
    int M, int K, const int* __restrict__ flagp)
{
  __shared__ u16 sh[64*264];           // 33 KB; K-loop: [As 2048][Bs 8192]; epilogue: 64x264 C tile
  u16* As = sh;
  u16* Bs = sh + 2048;
  int bf = *flagp;
  int a_bf = a_ext ? bf : 1;
  int tid = threadIdx.x;
  int lane = tid & 63, w = tid >> 6;
  int quad = lane >> 4, ln = lane & 15;
  int m0 = blockIdx.x * 64;

  f32x4v acc[4][4] = {};
  for (int k0 = 0; k0 < K; k0 += 32){
    // stage A tile 64x32 (convert to bf16 if needed)
    {
      int m = tid >> 2, g = tid & 3;
      int r = m0 + m;
      uint4 pack;
      if (r < M){
        size_t base = (size_t)r*K + k0 + g*8;
        if (a_bf){
          pack = *(const uint4*)((const u16*)A + base);
        } else {
          const float* Af = (const float*)A + base;
          float4 f0 = *(const float4*)Af;
          float4 f1 = *(const float4*)(Af+4);
          unsigned a0 = (unsigned)f2b(f0.x) | ((unsigned)f2b(f0.y)<<16);
          unsigned a1 = (unsigned)f2b(f0.z) | ((unsigned)f2b(f0.w)<<16);
          unsigned a2 = (unsigned)f2b(f1.x) | ((unsigned)f2b(f1.y)<<16);
          unsigned a3 = (unsigned)f2b(f1.z) | ((unsigned)f2b(f1.w)<<16);
          pack = make_uint4(a0,a1,a2,a3);
        }
      } else pack = make_uint4(0,0,0,0);
      ((uint4*)As)[tid] = pack;
    }
    // stage B tile 256x32 (already bf16, [n][k] layout)
    #pragma unroll
    for (int i=0;i<4;i++){
      int n = i*64 + (tid>>2), g = tid&3;
      ((uint4*)Bs)[i*256 + tid] = *(const uint4*)(Bt + (size_t)n*K + k0 + g*8);
    }
    __syncthreads();
    bf16x8 af[4], bfr[4];
    #pragma unroll
    for (int mi=0;mi<4;mi++) af[mi] = *(const bf16x8*)&As[(mi*16+ln)*32 + quad*8];
    #pragma unroll
    for (int nj=0;nj<4;nj++) bfr[nj] = *(const bf16x8*)&Bs[((size_t)w*64+nj*16+ln)*32 + quad*8];
    #pragma unroll
    for (int mi=0;mi<4;mi++)
      #pragma unroll
      for (int nj=0;nj<4;nj++)
        acc[mi][nj] = __builtin_amdgcn_mfma_f32_16x16x32_bf16(af[mi], bfr[nj], acc[mi][nj], 0,0,0);
    __syncthreads();
  }
  // dump accumulators to LDS (C/D layout: row=quad*4+reg, col=lane&15)
  #pragma unroll
  for (int mi=0;mi<4;mi++)
    #pragma unroll
    for (int nj=0;nj<4;nj++)
      #pragma unroll
      for (int r=0;r<4;r++)
        sh[(mi*16 + quad*4 + r)*264 + w*64 + nj*16 + ln] = f2b(acc[mi][nj][r]);
  __syncthreads();
  // coalesced bulk store of the 64x256 bf16 tile
  #pragma unroll
  for (int j=0;j<8;j++){
    int idx = j*256 + tid;
    int r = idx >> 5, gq = idx & 31;
    if (m0 + r < M)
      *(uint4*)(C + (size_t)(m0+r)*HC + gq*8) = *(const uint4*)&sh[r*264 + gq*8];
  }
  // per-row attention dots: wave w handles rows w*16..w*16+15
  float4 sv, dv;
  sv.x=ldf(att_s,lane*4+0,bf); sv.y=ldf(att_s,lane*4+1,bf);
  sv.z=ldf(att_s,lane*4+2,bf); sv.w=ldf(att_s,lane*4+3,bf);
  dv.x=ldf(att_d,lane*4+0,bf); dv.y=ldf(att_d,lane*4+1,bf);
  dv.z=ldf(att_d,lane*4+2,bf); dv.w=ldf(att_d,lane*4+3,bf);
  for (int rr=0; rr<16; rr++){
    int r = w*16 + rr;
    ushort4 u = *(const ushort4*)&sh[r*264 + lane*4];
    float ps = b2f(u.x)*sv.x + b2f(u.y)*sv.y + b2f(u.z)*sv.z + b2f(u.w)*sv.w;
    float pd = b2f(u.x)*dv.x + b2f(u.y)*dv.y + b2f(u.z)*dv.z + b2f(u.w)*dv.w;
    #pragma unroll
    for (int o=1;o<16;o<<=1){ ps+=__shfl_xor(ps,o); pd+=__shfl_xor(pd,o); }
    if ((lane&15)==0 && m0+r<M){
      a_s[(size_t)(m0+r)*4 + (lane>>4)] = ps;
      a_d[(size_t)(m0+r)*4 + (lane>>4)] = pd;
    }
  }
}

// ce[h] = sum_c We[h*C+c]*att_e[h*C+c]
__global__ void k_ce(const void* __restrict__ We, const void* __restrict__ att_e,
                     float* __restrict__ ce, const int* __restrict__ flagp){
  int bf = *flagp;
  int t=threadIdx.x;
  float p = ldf(We, t, bf)*ldf(att_e, t, bf);
  for(int o=32;o>0;o>>=1) p+=__shfl_xor(p,o);
  if((t&63)==0) ce[t>>6]=p;
}

// ---------------- fused segment softmax + aggregation + layer epilogue ----------------
// one wave per destination node, ZERO LDS. deg<=64: one edge per lane in registers,
// readlane-broadcast in the aggregation loop. deg>64: recompute fallback (never in practice).
// layer==1: +bias, l2norm, relu -> bf16 out (N x 256); layer==2: head-mean + bias -> out.
__global__ __launch_bounds__(256) void k_soft_agg(
    const u16* __restrict__ xs, const int* __restrict__ rowptr, const int* __restrict__ deg,
    const int* __restrict__ esrc, const float* __restrict__ eewf,
    const float* __restrict__ a_s, const float* __restrict__ a_d, const float* __restrict__ ce4,
    const void* __restrict__ bias, void* __restrict__ outp, int N, int layer,
    const int* __restrict__ flagp){
  int bf = *flagp;
  int lane = threadIdx.x & 63;
  int w = threadIdx.x >> 6;
  int n = (blockIdx.x<<2) + w;
  if (n >= N) return;
  int row = rowptr[n];
  int dg = deg[n];
  float4 ad = *(const float4*)&a_d[(size_t)n*4];
  float4 ce = *(const float4*)ce4;
  int h = lane >> 4;
  float4 acc = make_float4(0.f,0.f,0.f,0.f);
  if (dg > 0){
    if (dg <= 64){
      // --- softmax state fully in registers: lane p owns edge p ---
      int   s_reg = 0;
      float4 ar = make_float4(-1e30f,-1e30f,-1e30f,-1e30f);
      if (lane < dg){
        int pos = row + lane;
        int s = esrc[pos];
        if ((unsigned)s >= (unsigned)N) s = 0;
        s_reg = s;
        float wv = eewf[pos];
        float4 as = *(const float4*)&a_s[(size_t)s*4];
        ar.x = lrelu(as.x+ad.x+wv*ce.x);
        ar.y = lrelu(as.y+ad.y+wv*ce.y);
        ar.z = lrelu(as.z+ad.z+wv*ce.z);
        ar.w = lrelu(as.w+ad.w+wv*ce.w);
      }
      float4 m = wave_max4(ar);
      float4 ex = make_float4(0.f,0.f,0.f,0.f);
      if (lane < dg){
        ex.x=__expf(ar.x-m.x); ex.y=__expf(ar.y-m.y);
        ex.z=__expf(ar.z-m.z); ex.w=__expf(ar.w-m.w);
      }
      float4 ss = wave_sum4(ex);
      float4 wgt;
      wgt.x = ex.x/(ss.x+1e-16f); wgt.y = ex.y/(ss.y+1e-16f);
      wgt.z = ex.z/(ss.z+1e-16f); wgt.w = ex.w/(ss.w+1e-16f);
      // --- aggregation: broadcast lane e's (src, weight), gather row, fma. 4-way MLP ---
      int e = 0;
      for (; e+4 <= dg; e+=4){
        int s0=__builtin_amdgcn_readlane(s_reg,e+0);
        int s1=__builtin_amdgcn_readlane(s_reg,e+1);
        int s2=__builtin_amdgcn_readlane(s_reg,e+2);
        int s3=__builtin_amdgcn_readlane(s_reg,e+3);
        float w0=rdl_sel(wgt,h,e+0), w1=rdl_sel(wgt,h,e+1);
        float w2=rdl_sel(wgt,h,e+2), w3=rdl_sel(wgt,h,e+3);
        ushort4 x0 = *(const ushort4*)&xs[(size_t)s0*HC + lane*4];
        ushort4 x1 = *(const ushort4*)&xs[(size_t)s1*HC + lane*4];
        ushort4 x2 = *(const ushort4*)&xs[(size_t)s2*HC + lane*4];
        ushort4 x3 = *(const ushort4*)&xs[(size_t)s3*HC + lane*4];
        acc.x+=w0*b2f(x0.x); acc.y+=w0*b2f(x0.y); acc.z+=w0*b2f(x0.z); acc.w+=w0*b2f(x0.w);
        acc.x+=w1*b2f(x1.x); acc.y+=w1*b2f(x1.y); acc.z+=w1*b2f(x1.z); acc.w+=w1*b2f(x1.w);
        acc.x+=w2*b2f(x2.x); acc.y+=w2*b2f(x2.y); acc.z+=w2*b2f(x2.z); acc.w+=w2*b2f(x2.w);
        acc.x+=w3*b2f(x3.x); acc.y+=w3*b2f(x3.y); acc.z+=w3*b2f(x3.z); acc.w+=w3*b2f(x3.w);
      }
      for (; e<dg; e++){
        int s0=__builtin_amdgcn_readlane(s_reg,e);
        float w0=rdl_sel(wgt,h,e);
        ushort4 x0 = *(const ushort4*)&xs[(size_t)s0*HC + lane*4];
        acc.x+=w0*b2f(x0.x); acc.y+=w0*b2f(x0.y); acc.z+=w0*b2f(x0.z); acc.w+=w0*b2f(x0.w);
      }
    } else {
      // fallback: recompute (no LDS); statistically never taken at E/N=16
      float4 m = make_float4(-1e30f,-1e30f,-1e30f,-1e30f);
      for (int p=lane;p<dg;p+=64){
        int pos = row+p;
        int s = esrc[pos];
        if ((unsigned)s >= (unsigned)N) s = 0;
        float wv = eewf[pos];
        float4 as = *(const float4*)&a_s[(size_t)s*4];
        m.x=fmaxf(m.x, lrelu(as.x+ad.x+wv*ce.x));
        m.y=fmaxf(m.y, lrelu(as.y+ad.y+wv*ce.y));
        m.z=fmaxf(m.z, lrelu(as.z+ad.z+wv*ce.z));
        m.w=fmaxf(m.w, lrelu(as.w+ad.w+wv*ce.w));
      }
      m = wave_max4(m);
      float4 ss = make_float4(0.f,0.f,0.f,0.f);
      for (int p=lane;p<dg;p+=64){
        int pos = row+p;
        int s = esrc[pos];
        if ((unsigned)s >= (unsigned)N) s = 0;
        float wv = eewf[pos];
        float4 as = *(const float4*)&a_s[(size_t)s*4];
        ss.x+=__expf(lrelu(as.x+ad.x+wv*ce.x)-m.x);
        ss.y+=__expf(lrelu(as.y+ad.y+wv*ce.y)-m.y);
        ss.z+=__expf(lrelu(as.z+ad.z+wv*ce.z)-m.z);
        ss.w+=__expf(lrelu(as.w+ad.w+wv*ce.w)-m.w);
      }
      ss = wave_sum4(ss);
      float rsel=1.f/(sel4(ss,h)+1e-16f), mh=sel4(m,h), adh=sel4(ad,h), ceh=sel4(ce,h);
      for (int e=0;e<dg;e++){
        int pos=row+e;
        int s=esrc[pos];
        if ((unsigned)s >= (unsigned)N) s = 0;
        float wv=eewf[pos];
        float arv = lrelu(a_s[(size_t)s*4+h]+adh+wv*ceh);
        float wgt = __expf(arv-mh)*rsel;
        ushort4 xv4 = *(const ushort4*)&xs[(size_t)s*HC + lane*4];
        acc.x+=wgt*b2f(xv4.x); acc.y+=wgt*b2f(xv4.y);
        acc.z+=wgt*b2f(xv4.z); acc.w+=wgt*b2f(xv4.w);
      }
    }
  }
  if (layer==1){
    // h = relu(l2norm(acc + b1)) -> bf16
    float4 v;
    v.x = acc.x + ldf(bias, lane*4+0, bf);
    v.y = acc.y + ldf(bias, lane*4+1, bf);
    v.z = acc.z + ldf(bias, lane*4+2, bf);
    v.w = acc.w + ldf(bias, lane*4+3, bf);
    float ss = v.x*v.x+v.y*v.y+v.z*v.z+v.w*v.w;
    #pragma unroll
    for(int o=32;o>0;o>>=1) ss += __shfl_xor(ss,o);
    float inv = 1.f/fmaxf(sqrtf(ss), 1e-12f);
    ushort4 o4;
    o4.x = f2b(fmaxf(v.x*inv,0.f)); o4.y = f2b(fmaxf(v.y*inv,0.f));
    o4.z = f2b(fmaxf(v.z*inv,0.f)); o4.w = f2b(fmaxf(v.w*inv,0.f));
    *(ushort4*)((u16*)outp + (size_t)n*HC + lane*4) = o4;
  } else {
    // mean over heads + b2 -> final output
    float4 s = acc;
    #pragma unroll
    for (int o=16;o<=32;o<<=1){
      s.x+=__shfl_xor(s.x,o); s.y+=__shfl_xor(s.y,o);
      s.z+=__shfl_xor(s.z,o); s.w+=__shfl_xor(s.w,o);
    }
    if (lane < 16){
      float4 v;
      v.x = 0.25f*s.x + ldf(bias, lane*4+0, bf);
      v.y = 0.25f*s.y + ldf(bias, lane*4+1, bf);
      v.z = 0.25f*s.z + ldf(bias, lane*4+2, bf);
      v.w = 0.25f*s.w + ldf(bias, lane*4+3, bf);
      if (bf){
        ushort4 o4; o4.x=f2b(v.x); o4.y=f2b(v.y); o4.z=f2b(v.z); o4.w=f2b(v.w);
        *(ushort4*)((u16*)outp + (size_t)n*CDIM + lane*4) = o4;
      } else {
        *(float4*)((float*)outp + (size_t)n*CDIM + lane*4) = v;
      }
    }
  }
}

extern "C" void kernel_launch(void* const* d_in, const int* in_sizes, int n_in,
                              void* d_out, int out_size, void* d_ws, size_t ws_size,
                              hipStream_t stream){
  const void* x_in = d_in[0];
  const int* eidx  = (const int*)d_in[1];
  const void* ew   = d_in[2];
  const void* W1   = d_in[3];
  const void* as1  = d_in[4];
  const void* ad1  = d_in[5];
  const void* We1  = d_in[6];
  const void* ae1  = d_in[7];
  const void* b1   = d_in[8];
  const void* W2   = d_in[9];
  const void* as2  = d_in[10];
  const void* ad2  = d_in[11];
  const void* We2  = d_in[12];
  const void* ae2  = d_in[13];
  const void* b2   = d_in[14];

  int N = in_sizes[0]/128;
  int E = in_sizes[2];
  const int* src = eidx;
  const int* dst = eidx + E;

  char* w = (char*)d_ws;
  auto alloc = [&](size_t bytes)->char*{ char* p=w; w += (bytes+255)/256*256; return p; };
  int*   flag  = (int*)alloc(256);
  u16*   xs    = (u16*)alloc((size_t)N*HC*2);   // bf16 feature buffer A
  u16*   agg   = (u16*)alloc((size_t)N*HC*2);   // bf16 feature buffer B (h)
  float* a_s   = (float*)alloc((size_t)N*4*4);
  float* a_d   = (float*)alloc((size_t)N*4*4);
  int*   deg   = (int*)alloc((size_t)N*4);
  int*   cursor= (int*)alloc((size_t)N*4);
  int*   rowptr= (int*)alloc((size_t)N*4);
  int*   bsums = (int*)alloc(256*4);
  int*   esrc  = (int*)alloc((size_t)E*4);
  float* eewf  = (float*)alloc((size_t)E*4);
  float* ce    = (float*)alloc(64);
  u16*   Bt1   = (u16*)alloc((size_t)HC*128*2); // W1^T bf16 [256][128]
  u16*   Bt2   = (u16*)alloc((size_t)HC*HC*2);  // W2^T bf16 [256][256]

  hipMemsetAsync(deg, 0, (size_t)N*4, stream);
  hipMemsetAsync(cursor, 0, (size_t)N*4, stream);

  k_detect<<<1,256,0,stream>>>((const u16*)x_in, in_sizes[0], flag);

  int eb = (E+255)/256;
  int nb = (N+255)/256;
  k_hist<<<eb,256,0,stream>>>(dst, E, N, deg);
  k_scan1<<<nb,256,0,stream>>>(deg, rowptr, bsums, N);
  k_scan2<<<1,256,0,stream>>>(bsums, nb);
  k_scan3<<<nb,256,0,stream>>>(rowptr, bsums, N);
  k_scatter<<<eb,256,0,stream>>>(src, dst, ew, E, N, rowptr, cursor, esrc, eewf, flag);
  k_prepB<<<128,256,0,stream>>>(W1, Bt1, 128, flag);
  k_prepB<<<256,256,0,stream>>>(W2, Bt2, 256, flag);

  int gemmBlocks = (N+63)/64;
  int nwb = (N+3)/4;   // 4 node-waves per block

  // ---- layer 1 ----
  k_gemm_mfma<<<gemmBlocks,256,0,stream>>>(x_in, 1, Bt1, xs, as1, ad1, a_s, a_d, N, 128, flag);
  k_ce<<<1,256,0,stream>>>(We1, ae1, ce, flag);
  k_soft_agg<<<nwb,256,0,stream>>>(xs, rowptr, deg, esrc, eewf, a_s, a_d, ce, b1, agg, N, 1, flag);

  // ---- layer 2 ----
  k_gemm_mfma<<<gemmBlocks,256,0,stream>>>(agg, 0, Bt2, xs, as2, ad2, a_s, a_d, N, 256, flag);
  k_ce<<<1,256,0,stream>>>(We2, ae2, ce, flag);
  k_soft_agg<<<nwb,256,0,stream>>>(xs, rowptr, deg, esrc, eewf, a_s, a_d, ce, b2, d_out, N, 2, flag);
}